// Round 11
// baseline (718.714 us; speedup 1.0000x reference)
//
#include <hip/hip_runtime.h>
#include <hip/hip_bf16.h>

#define Tn 1024
#define Bn 64
#define En 128
#define G4 512
#define NEGV -10000.0f

typedef short bh8 __attribute__((ext_vector_type(8)));
typedef float fl4 __attribute__((ext_vector_type(4)));
typedef int i8v __attribute__((ext_vector_type(8)));

// ---------- fast transcendental primitives ----------
#if __has_builtin(__builtin_amdgcn_exp2f)
#define EXP2(x) __builtin_amdgcn_exp2f(x)
#else
#define EXP2(x) exp2f(x)
#endif
#if __has_builtin(__builtin_amdgcn_rcpf)
#define RCP(x) __builtin_amdgcn_rcpf(x)
#else
#define RCP(x) (1.0f / (x))
#endif

#define LOG2E  1.4426950408889634f
#define LOG2E2 2.8853900817779268f

// ---------- bf16 helpers ----------
__device__ __forceinline__ float bf2f(unsigned short u) {
    unsigned int v = ((unsigned int)u) << 16;
    float f;
    __builtin_memcpy(&f, &v, 4);
    return f;
}
__device__ __forceinline__ unsigned short f2bf(float f) {
    unsigned int u;
    __builtin_memcpy(&u, &f, 4);
    u = (u + 0x7fffu + ((u >> 16) & 1u)) >> 16;
    return (unsigned short)u;
}
// hw packed f32x2 -> bf16x2 (RNE, same as manual f2bf)
__device__ __forceinline__ unsigned cvt_pk_bf16(float lo, float hi) {
    unsigned r;
    asm("v_cvt_pk_bf16_f32 %0, %1, %2" : "=v"(r) : "v"(lo), "v"(hi));
    return r;
}
__device__ __forceinline__ unsigned short f2bf_hw(float x) {
    return (unsigned short)(cvt_pk_bf16(x, 0.0f) & 0xffffu);
}
__device__ __forceinline__ float asf(unsigned int u) {
    float f;
    __builtin_memcpy(&f, &u, 4);
    return f;
}
__device__ __forceinline__ float i2f(int u) {
    float f;
    __builtin_memcpy(&f, &u, 4);
    return f;
}
__device__ __forceinline__ int f2i(float f) {
    int u;
    __builtin_memcpy(&u, &f, 4);
    return u;
}

// ---------- fp8 e4m3fn encode ----------
__device__ __forceinline__ unsigned char f8enc(float x) {
#if __has_builtin(__builtin_amdgcn_cvt_pk_fp8_f32)
    int pk = __builtin_amdgcn_cvt_pk_fp8_f32(x, 0.0f, 0, false);
    return (unsigned char)(pk & 0xff);
#else
    // manual OCP e4m3fn (RNE): max 448, min normal 2^-6, subnormal step 2^-9
    unsigned u;
    __builtin_memcpy(&u, &x, 4);
    unsigned s = (u >> 31) << 7;
    float a = fabsf(x);
    if (!(a > 0.0f)) return (unsigned char)s;
    if (a >= 464.0f) return (unsigned char)(s | 0x7E);
    if (a < 0.015625f) {
        int q = (int)rintf(a * 512.0f);
        return (unsigned char)(s | (unsigned)q);
    }
    int ex;
    (void)frexpf(a, &ex);
    int E = ex - 1;
    float t = ldexpf(a, -E);
    int m3 = (int)rintf((t - 1.0f) * 8.0f);
    if (m3 == 8) { m3 = 0; E += 1; }
    if (E > 8) return (unsigned char)(s | 0x7E);
    return (unsigned char)(s | ((unsigned)(E + 7) << 3) | (unsigned)m3);
#endif
}

// lgkm-only barrier: LDS visibility without draining vmcnt.
// imm 0xC07F = vmcnt(63) expcnt(7) lgkmcnt(0).
__device__ __forceinline__ void barrier_lds_only() {
    __builtin_amdgcn_s_waitcnt(0xC07F);
    __builtin_amdgcn_s_barrier();
}

// =====================================================================
// K0: one-time weight conversion.
// i < 131072:    whh (fp32 [512][128], both dirs) -> fp8 e4m3 scaled x64.
// i >= 131072:   w_ih (both dirs) -> bf16, PACKED-PERMUTED rows:
//                wihP[dir][np][k] = bf16(w_ih_dir[((np&3)<<7)+(np>>2)][k])
//                so k_inproj's B staging is a raw copy (no cvt, no permute).
// =====================================================================
__global__ __launch_bounds__(256) void k_wcvt(
    const float* __restrict__ wf, const float* __restrict__ wb,
    const float* __restrict__ wih_f, const float* __restrict__ wih_b,
    unsigned char* __restrict__ o, unsigned short* __restrict__ wihP)
{
    const int i = blockIdx.x * 256 + threadIdx.x;   // 0 .. 262143
    if (i < 131072) {
        const float v = (i < 65536) ? wf[i] : wb[i - 65536];
        o[i] = f8enc(v * 64.0f);
    } else {
        const int j = i - 131072;                   // 0 .. 131071
        const int dir = j >> 16;
        const int np = (j >> 7) & 511;
        const int k = j & 127;
        const int norig = ((np & 3) << 7) + (np >> 2);
        const float* w = dir ? wih_b : wih_f;
        wihP[j] = f2bf_hw(w[norig * 128 + k]);
    }
}

// =====================================================================
// K1: input projection via bf16 MFMA — R17 structure (unchanged).
// Grid 512 (one WG per 128-row tile). A staged ONCE; loop over the
// 8 (dir,nt) B-chunks with double-buffered LDS B. B pre-converted bf16
// packed-permuted by k_wcvt => staging is pure uint4 copies.
// G stored pre-scaled by log2e (i,f,o) / 2*log2e (g), layout [t][b][j][gate].
// G-store coalescing note: per row, wave w's ni-pair fills the aligned
// 64B line [w*32 .. w*32+32) ushorts => writes already line-efficient.
// =====================================================================
__global__ __launch_bounds__(256) void k_inproj(
    const int* __restrict__ sent, const float* __restrict__ embed,
    const unsigned short* __restrict__ wihP,
    const float* __restrict__ b_ih_f, const float* __restrict__ b_hh_f,
    const float* __restrict__ b_ih_b, const float* __restrict__ b_hh_b,
    unsigned short* __restrict__ G_f, unsigned short* __restrict__ G_b)
{
    __shared__ unsigned short Asm[128][136];
    __shared__ unsigned short Bsm[2][128][136];
    const int tid = threadIdx.x;
    const int mt = blockIdx.x;
    const int r0 = mt * 128;

    // ---- stage A once: rows r0..r0+127 of embed[token] as bf16 ----
    {
        const int srow = tid >> 1;
        const int ch = (tid & 1) * 64;
        const int rg = r0 + srow;
        const int tt = rg >> 6, bb = rg & 63;
        const int tok = sent[bb * Tn + tt];
        const float* ar = embed + (size_t)tok * En + ch;
#pragma unroll
        for (int i = 0; i < 64; i += 4) {
            float4 v = *(const float4*)(ar + i);
            *(unsigned*)&Asm[srow][ch + i]     = cvt_pk_bf16(v.x, v.y);
            *(unsigned*)&Asm[srow][ch + i + 2] = cvt_pk_bf16(v.z, v.w);
        }
    }

    // ---- B chunk staging: raw bf16 copy (128 rows x 128 cols) ----
    const int brow = tid >> 1;
    const int bhalf = (tid & 1) * 64;
#define STAGE_B(cidx)                                                          \
    {                                                                          \
        const int d_ = (cidx) >> 2, nt_ = (cidx) & 3, pb_ = (cidx) & 1;        \
        const uint4* s4 = (const uint4*)(wihP + ((size_t)d_ << 16) +           \
                          (size_t)(nt_ * 128 + brow) * 128 + bhalf);           \
        uint4* d4 = (uint4*)&Bsm[pb_][brow][bhalf];                            \
        _Pragma("unroll")                                                      \
        for (int ii = 0; ii < 8; ++ii) d4[ii] = s4[ii];                        \
    }

    STAGE_B(0);
    __syncthreads();

    const int w = tid >> 6, lane = tid & 63;
    const int ln = lane & 15, lq = lane >> 4;
    const int nwb = w * 32;

    for (int cidx = 0; cidx < 8; ++cidx) {
        if (cidx + 1 < 8) STAGE_B(cidx + 1);   // prefetch next chunk (other buffer)
        const int dir = cidx >> 2, nt = cidx & 3, pb = cidx & 1;

        fl4 acc[8][2];
#pragma unroll
        for (int mi = 0; mi < 8; ++mi)
#pragma unroll
            for (int ni = 0; ni < 2; ++ni) acc[mi][ni] = (fl4){0.f, 0.f, 0.f, 0.f};

#pragma unroll
        for (int kt = 0; kt < 4; ++kt) {
            const int kc = kt * 32 + lq * 8;
            bh8 a[8], bf[2];
#pragma unroll
            for (int mi = 0; mi < 8; ++mi) a[mi] = *(const bh8*)&Asm[mi * 16 + ln][kc];
#pragma unroll
            for (int ni = 0; ni < 2; ++ni) bf[ni] = *(const bh8*)&Bsm[pb][nwb + ni * 16 + ln][kc];
#pragma unroll
            for (int mi = 0; mi < 8; ++mi)
#pragma unroll
                for (int ni = 0; ni < 2; ++ni)
                    acc[mi][ni] = __builtin_amdgcn_mfma_f32_16x16x32_bf16(a[mi], bf[ni], acc[mi][ni], 0, 0, 0);
        }

        const float* bi = dir ? b_ih_b : b_ih_f;
        const float* bh = dir ? b_hh_b : b_hh_f;
        unsigned short* Gout = dir ? G_b : G_f;

        float bias[2], gsc[2];
#pragma unroll
        for (int ni = 0; ni < 2; ++ni) {
            const int np = nt * 128 + nwb + ni * 16 + ln;   // packed index j*4+gate
            const int norig = ((np & 3) << 7) + (np >> 2);
            bias[ni] = bi[norig] + bh[norig];
            gsc[ni] = ((np & 3) == 2) ? LOG2E2 : LOG2E;     // gate g gets 2*log2e
        }
#pragma unroll
        for (int mi = 0; mi < 8; ++mi)
#pragma unroll
            for (int ni = 0; ni < 2; ++ni) {
                const int np = nt * 128 + nwb + ni * 16 + ln;
#pragma unroll
                for (int rg = 0; rg < 4; ++rg) {
                    const int m = mi * 16 + lq * 4 + rg;
                    const size_t r = (size_t)(r0 + m);
                    Gout[(r << 9) + np] = f2bf_hw((acc[mi][ni][rg] + bias[ni]) * gsc[ni]);
                }
            }

        __syncthreads();   // chunk done: staged buffer ready, old buffer free
    }
#undef STAGE_B
}

// =====================================================================
// K2: LSTM recurrence — R21 structure (349.0 us).
// Structural ledger (do NOT retry): R13 lockstep dual-dir (1008us),
// R18 spin-poll dual-dir (646us + 31ms stalls); 2-chains-per-CU pays
// ~+598cyc issue to hide <=290cyc latency => dead. Wave-split variants
// dead by redundancy arithmetic. Multi-batch-per-WG can't cut wall.
// fp4/fp6-rate paths need low-precision h => dead.
// Step model ~820 cyc: 276 MFMA-issue + ~280 VALU/TRANS-issue +
// ~260 serial-chain latency. setprio(1) around MFMA: -21us (R21).
// R22 (this round): (a) setprio window extended to cover the ha
// ds_read feeding the MFMAs; (b) h-store split across quads — all 4
// quads compute bit-identical hn (bpermute indices depend only on ln,
// so iv/fv/tg/ov and c replicate across quads): quad0 does the LDS
// write (barrier-gated), quad1 does the global store, in parallel.
// =====================================================================
__global__ __launch_bounds__(512, 2) void k_lstm(
    const unsigned char* __restrict__ whh8,
    const unsigned short* __restrict__ G_f, const unsigned short* __restrict__ G_b,
    unsigned short* __restrict__ h_f, unsigned short* __restrict__ h_b)
{
    const int tid = threadIdx.x;
    const int w = tid >> 6;
    const int lane = tid & 63;
    const int ln = lane & 15;
    const int quad = lane >> 4;
    const int b = blockIdx.x;           // batch
    const int dir = blockIdx.y;
    const unsigned short* Gd = dir ? G_b : G_f;
    unsigned short* ho = dir ? h_b : h_f;

    const int j = w * 16 + ln;          // this lane's h index (gate column)

    __shared__ __align__(16) unsigned char hls8[2][128];   // fp8 h (x16), double-buffered

    // ---- weights (B-frags): lane provides B[k=quad*32+i][n=ln] = W8[q*128+j][quad*32+i]
    const unsigned char* wb8 = whh8 + (size_t)dir * 65536 + quad * 32;
    const i8v w0 = *(const i8v*)(wb8 + ((size_t)(0 * 128 + j) << 7));
    const i8v w1 = *(const i8v*)(wb8 + ((size_t)(1 * 128 + j) << 7));
    const i8v w2 = *(const i8v*)(wb8 + ((size_t)(2 * 128 + j) << 7));
    const i8v w3 = *(const i8v*)(wb8 + ((size_t)(3 * 128 + j) << 7));

    // zero both h buffers (2*128 fp8 = 64 dwords); fp8 0x00 == 0.0
    if (tid < 64) ((unsigned*)hls8)[tid] = 0u;
    float c = 0.0f;
    __syncthreads();

    // ---- running pointers (strength-reduced; dir sign hoisted) ----
    const int t0 = dir ? (Tn - 1) : 0;
    const ptrdiff_t gstep = dir ? -(ptrdiff_t)(Bn << 9) : (ptrdiff_t)(Bn << 9);   // ushorts/step
    const ptrdiff_t hstep = dir ? -(ptrdiff_t)(Bn << 7) : (ptrdiff_t)(Bn << 7);   // ushorts/step
    const unsigned short* gptr = Gd + (((size_t)t0 * Bn + b) << 9) + (j << 2);
    unsigned short* hptr = ho + (((size_t)t0 * Bn + b) << 7) + j;

    // ---- G pipeline preload: slot u = packed gates [i|f] [g|o] of step u ----
    uint2 gp[4];
#pragma unroll
    for (int u = 0; u < 4; ++u) {
        gp[u] = *(const uint2*)gptr;
        gptr += gstep;
    }
    // gptr now points at step 4

    const float dsL  = 0.0009765625f * LOG2E;    // 1/(64*16) descale, log2e-folded
    const float ds2L = 0.0009765625f * LOG2E2;   // g-gate descale

    // ---- lane-constant activation params (quad q owns gate q) ----
    const float cds = (quad == 2) ? ds2L : -dsL;
    const unsigned gsign = (quad == 2) ? 0u : 0x80000000u;
    const int gshift = (quad & 1) ? 0 : 16;
    const int bp0 = (0 * 16 + ln) << 2;     // bpermute byte addrs (lane*4)
    const int bp1 = (1 * 16 + ln) << 2;
    const int bp2 = (2 * 16 + ln) << 2;
    const int bp3 = (3 * 16 + ln) << 2;

    for (int blk = 0; blk < Tn / 4; ++blk) {
#pragma unroll
        for (int u = 0; u < 4; ++u) {
            const int s = blk * 4 + u;
            const int p = u & 1;          // h buffer parity (blk*4 is even)

            // consume slot u (loaded at step s-4)
            const uint2 gv = gp[u];

            // prefetch step s+4 into slot u (running pointer, static slot)
            if (s + 4 < Tn) {
                gp[u] = *(const uint2*)gptr;
                gptr += gstep;
            }

            // ---- prioritized window: A-frag ds_read + 4 MFMAs ----
            __builtin_amdgcn_s_setprio(1);
            const i8v ha = *(const i8v*)&hls8[p][quad * 32];

            // ---- 4 INDEPENDENT K=128 fp8 MFMAs: aq = dot(h, W[q*128+j]) * 1024
            const fl4 z = (fl4){0.f, 0.f, 0.f, 0.f};
            fl4 a0 = __builtin_amdgcn_mfma_scale_f32_16x16x128_f8f6f4(
                         ha, w0, z, 0, 0, 0, 0x7F7F7F7F, 0, 0x7F7F7F7F);
            fl4 a1 = __builtin_amdgcn_mfma_scale_f32_16x16x128_f8f6f4(
                         ha, w1, z, 0, 0, 0, 0x7F7F7F7F, 0, 0x7F7F7F7F);
            fl4 a2 = __builtin_amdgcn_mfma_scale_f32_16x16x128_f8f6f4(
                         ha, w2, z, 0, 0, 0, 0x7F7F7F7F, 0, 0x7F7F7F7F);
            fl4 a3 = __builtin_amdgcn_mfma_scale_f32_16x16x128_f8f6f4(
                         ha, w3, z, 0, 0, 0, 0x7F7F7F7F, 0, 0x7F7F7F7F);
            __builtin_amdgcn_s_setprio(0);

            // ---- quad-specialized activation: own gate only ----
            float a01 = (quad & 1) ? a1[0] : a0[0];
            float a23 = (quad & 1) ? a3[0] : a2[0];
            float aown = (quad & 2) ? a23 : a01;
            unsigned wsel = (quad & 2) ? gv.y : gv.x;
            unsigned gb = ((wsel << gshift) & 0xffff0000u) ^ gsign;
            float pre = __builtin_fmaf(aown, cds, asf(gb));
            float tq = RCP(1.0f + EXP2(pre));
            // gather all four gate results to every lane (wave crossbar)
            int tqi = f2i(tq);
            float iv = i2f(__builtin_amdgcn_ds_bpermute(bp0, tqi));
            float fv = i2f(__builtin_amdgcn_ds_bpermute(bp1, tqi));
            float tg = i2f(__builtin_amdgcn_ds_bpermute(bp2, tqi));
            float ov = i2f(__builtin_amdgcn_ds_bpermute(bp3, tqi));
            float ov16 = ov * 16.0f;                       // off-chain pow2 scale
            float gvv = __builtin_fmaf(-2.0f, tg, 1.0f);
            c = __builtin_fmaf(fv, c, iv * gvv);
            float r2 = RCP(1.0f + EXP2(c * LOG2E2));
            float th = __builtin_fmaf(-2.0f, r2, 1.0f);

            // ---- h writes, split across quads (hn is quad-replicated):
            //      quad0 -> LDS fp8 (barrier-gated); quad1 -> global bf16
            if (quad == 0) {
                hls8[1 - p][j] = f8enc(ov16 * th);         // == f8enc((ov*th)*16)
            } else if (quad == 1) {
                *hptr = f2bf_hw(ov * th);
            }
            hptr += hstep;

            barrier_lds_only();
        }
    }
}

// =====================================================================
// K3: feats. Output layout featsT[b][t][n] (b*9216 + t*9 + n) so
// k_viterbi's per-batch staging is contiguous float4 loads.
// =====================================================================
__global__ __launch_bounds__(256) void k_feats(
    const unsigned short* __restrict__ h_f, const unsigned short* __restrict__ h_b,
    const float* __restrict__ w_out, const float* __restrict__ b_out,
    float* __restrict__ feats)
{
    __shared__ float wl[256][12];
    __shared__ float bl[12];
    const int tid = threadIdx.x;
#pragma unroll
    for (int s = 0; s < 9; ++s) wl[tid][s] = w_out[s * 256 + tid];
#pragma unroll
    for (int s = 9; s < 12; ++s) wl[tid][s] = 0.0f;
    if (tid < 12) bl[tid] = (tid < 9) ? b_out[tid] : 0.0f;
    __syncthreads();

    const int r = blockIdx.x * 256 + tid;
    const unsigned short* hfr = h_f + (size_t)r * 128;
    const unsigned short* hbr = h_b + (size_t)r * 128;
    float acc[12];
#pragma unroll
    for (int k = 0; k < 12; ++k) acc[k] = bl[k];

    for (int ch = 0; ch < 32; ++ch) {
        const unsigned short* src = (ch < 16) ? (hfr + ch * 8) : (hbr + (ch - 16) * 8);
        uint4 hv = *(const uint4*)src;
        unsigned int hw0 = hv.x, hw1 = hv.y, hw2 = hv.z, hw3 = hv.w;
        const int jb = ch * 8;
#pragma unroll
        for (int q = 0; q < 8; ++q) {
            unsigned int word = (q < 2) ? hw0 : ((q < 4) ? hw1 : ((q < 6) ? hw2 : hw3));
            unsigned short hs = (q & 1) ? (unsigned short)(word >> 16) : (unsigned short)(word & 0xffff);
            float hf = bf2f(hs);
            const float* wrp = &wl[jb + q][0];
            float4 w0 = *(const float4*)(wrp);
            float4 w1 = *(const float4*)(wrp + 4);
            float4 w2 = *(const float4*)(wrp + 8);
            acc[0] += hf * w0.x; acc[1] += hf * w0.y; acc[2] += hf * w0.z; acc[3] += hf * w0.w;
            acc[4] += hf * w1.x; acc[5] += hf * w1.y; acc[6] += hf * w1.z; acc[7] += hf * w1.w;
            acc[8] += hf * w2.x; acc[9] += hf * w2.y; acc[10] += hf * w2.z; acc[11] += hf * w2.w;
        }
    }
    const int t = r >> 6, b = r & 63;                 // r = t*64 + b
    float* fr = feats + (size_t)b * 9216 + (size_t)t * 9;
#pragma unroll
    for (int k = 0; k < 9; ++k) fr[k] = acc[k];
}

// =====================================================================
// K4: Viterbi (R21: running pointers, max3 chain, eq-cascade
// backpointer, coalesced featsT staging — unchanged).
// =====================================================================
__global__ __launch_bounds__(64) void k_viterbi(
    const float* __restrict__ feats, const float* __restrict__ trans,
    float* __restrict__ out)
{
    __shared__ __align__(16) unsigned char bp[1024 * 16];
    __shared__ __align__(16) float fl[1024 * 9];
    __shared__ unsigned char pt[1024];    // also absorbs the t=1023 overread of fl

    const int b = blockIdx.x, tid = threadIdx.x;

    // coalesced staging: featsT[b][0..9215] contiguous, 16B per lane
    {
        const float4* fsrc = (const float4*)(feats + (size_t)b * 9216);
        float4* fdst = (float4*)fl;
        for (int i = tid; i < 2304; i += 64) fdst[i] = fsrc[i];
    }

    const int n9 = (tid < 9) ? tid : 8;   // clamp so inactive lanes stay valid
    float trn[9];
#pragma unroll
    for (int p = 0; p < 9; ++p) trn[p] = trans[n9 * 9 + p];
    float trs = (tid < 9) ? trans[8 * 9 + tid] : -3.0e38f;

    float delta = (n9 == 7) ? 0.0f : NEGV;   // START=7
    __syncthreads();

    const float* fp = &fl[n9];                // running feats pointer
    unsigned char* bpp = &bp[tid];            // running bp pointer
    float fnext = *fp;                        // feats for t=0
    for (int t = 0; t < 1024; ++t) {
        // gather all 9 previous deltas (in-register wave crossbar)
        float d0 = __shfl(delta, 0, 64);
        float d1 = __shfl(delta, 1, 64);
        float d2 = __shfl(delta, 2, 64);
        float d3 = __shfl(delta, 3, 64);
        float d4 = __shfl(delta, 4, 64);
        float d5 = __shfl(delta, 5, 64);
        float d6 = __shfl(delta, 6, 64);
        float d7 = __shfl(delta, 7, 64);
        float d8 = __shfl(delta, 8, 64);
        float fhere = fnext;
        fp += 9;
        fnext = *fp;                          // t=1023: lands in pt[], unused

        float s0 = d0 + trn[0], s1 = d1 + trn[1], s2 = d2 + trn[2];
        float s3 = d3 + trn[3], s4 = d4 + trn[4], s5 = d5 + trn[5];
        float s6 = d6 + trn[6], s7 = d7 + trn[7], s8 = d8 + trn[8];

        // recurrence chain: max via fused max3 levels (exact)
        float m012 = fmaxf(fmaxf(s0, s1), s2);
        float m345 = fmaxf(fmaxf(s3, s4), s5);
        float m678 = fmaxf(fmaxf(s6, s7), s8);
        float m = fmaxf(fmaxf(m012, m345), m678);
        delta = m + fhere;

        // backpointer: eq-match cascade (descending) -> first index == m
        int am = 8;
        am = (s7 == m) ? 7 : am;
        am = (s6 == m) ? 6 : am;
        am = (s5 == m) ? 5 : am;
        am = (s4 == m) ? 4 : am;
        am = (s3 == m) ? 3 : am;
        am = (s2 == m) ? 2 : am;
        am = (s1 == m) ? 1 : am;
        am = (s0 == m) ? 0 : am;

        if (tid < 9) *bpp = (unsigned char)am;
        bpp += 16;
    }

    float tv = (tid < 9) ? (delta + trs) : -3.0e38f;
    int bi = tid;
#pragma unroll
    for (int off = 8; off >= 1; off >>= 1) {
        float ov = __shfl_down(tv, off, 64);
        int oi = __shfl_down(bi, off, 64);
        if (ov > tv || (ov == tv && oi < bi)) { tv = ov; bi = oi; }
    }
    int best = __shfl(bi, 0, 64);
    if (tid == 0) out[b] = tv;

    if (tid == 0) {
        int tag = best;
        for (int t0 = 1023; t0 >= 0; t0 -= 8) {
            uint4 rows[8];
#pragma unroll
            for (int i = 0; i < 8; ++i) rows[i] = *(const uint4*)&bp[(t0 - i) * 16];
#pragma unroll
            for (int i = 0; i < 8; ++i) {
                pt[t0 - i] = (unsigned char)tag;
                uint4 rw = rows[i];
                unsigned int sel = (unsigned int)tag >> 2;
                unsigned int word = (sel == 0) ? rw.x : ((sel == 1) ? rw.y : rw.z);
                tag = (int)((word >> ((tag & 3) * 8)) & 0xffu);
            }
        }
    }
    for (int i = tid; i < 1024; i += 64) {
        out[64 + b * 1024 + i] = (float)pt[i];
    }
}

// =====================================================================
extern "C" void kernel_launch(void* const* d_in, const int* in_sizes, int n_in,
                              void* d_out, int out_size, void* d_ws, size_t ws_size,
                              hipStream_t stream) {
    const int*   sent   = (const int*)d_in[0];
    const float* embed  = (const float*)d_in[1];
    const float* w_ih_f = (const float*)d_in[2];
    const float* w_hh_f = (const float*)d_in[3];
    const float* b_ih_f = (const float*)d_in[4];
    const float* b_hh_f = (const float*)d_in[5];
    const float* w_ih_b = (const float*)d_in[6];
    const float* w_hh_b = (const float*)d_in[7];
    const float* b_ih_b = (const float*)d_in[8];
    const float* b_hh_b = (const float*)d_in[9];
    const float* w_out  = (const float*)d_in[10];
    const float* b_out  = (const float*)d_in[11];
    const float* trans  = (const float*)d_in[12];
    float* out = (float*)d_out;

    unsigned short* G_f = (unsigned short*)d_ws;
    unsigned short* G_b = G_f + (size_t)Tn * Bn * G4;
    unsigned short* h_f = G_b + (size_t)Tn * Bn * G4;
    unsigned short* h_b = h_f + (size_t)Tn * Bn * 128;
    float* feats = (float*)(h_b + (size_t)Tn * Bn * 128);
    unsigned char* whh8 = (unsigned char*)(feats + (size_t)Tn * Bn * 9);
    unsigned short* wihP = (unsigned short*)(whh8 + 131072);

    k_wcvt<<<1024, 256, 0, stream>>>(w_hh_f, w_hh_b, w_ih_f, w_ih_b, whh8, wihP);
    k_inproj<<<512, 256, 0, stream>>>(sent, embed, wihP,
        b_ih_f, b_hh_f, b_ih_b, b_hh_b, G_f, G_b);
    k_lstm<<<dim3(64, 2), 512, 0, stream>>>(whh8, G_f, G_b, h_f, h_b);
    k_feats<<<256, 256, 0, stream>>>(h_f, h_b, w_out, b_out, feats);
    k_viterbi<<<64, 64, 0, stream>>>(feats, trans, out);
}

// Round 12
// 688.438 us; speedup vs baseline: 1.0440x; 1.0440x over previous
//
#include <hip/hip_runtime.h>
#include <hip/hip_bf16.h>

#define Tn 1024
#define Bn 64
#define En 128
#define G4 512
#define NEGV -10000.0f

typedef short bh8 __attribute__((ext_vector_type(8)));
typedef float fl4 __attribute__((ext_vector_type(4)));
typedef int i8v __attribute__((ext_vector_type(8)));

// ---------- fast transcendental primitives ----------
#if __has_builtin(__builtin_amdgcn_exp2f)
#define EXP2(x) __builtin_amdgcn_exp2f(x)
#else
#define EXP2(x) exp2f(x)
#endif
#if __has_builtin(__builtin_amdgcn_rcpf)
#define RCP(x) __builtin_amdgcn_rcpf(x)
#else
#define RCP(x) (1.0f / (x))
#endif

#define LOG2E  1.4426950408889634f
#define LOG2E2 2.8853900817779268f

// ---------- bf16 helpers ----------
__device__ __forceinline__ float bf2f(unsigned short u) {
    unsigned int v = ((unsigned int)u) << 16;
    float f;
    __builtin_memcpy(&f, &v, 4);
    return f;
}
__device__ __forceinline__ unsigned short f2bf(float f) {
    unsigned int u;
    __builtin_memcpy(&u, &f, 4);
    u = (u + 0x7fffu + ((u >> 16) & 1u)) >> 16;
    return (unsigned short)u;
}
// hw packed f32x2 -> bf16x2 (RNE, same as manual f2bf)
__device__ __forceinline__ unsigned cvt_pk_bf16(float lo, float hi) {
    unsigned r;
    asm("v_cvt_pk_bf16_f32 %0, %1, %2" : "=v"(r) : "v"(lo), "v"(hi));
    return r;
}
__device__ __forceinline__ unsigned short f2bf_hw(float x) {
    return (unsigned short)(cvt_pk_bf16(x, 0.0f) & 0xffffu);
}
__device__ __forceinline__ float asf(unsigned int u) {
    float f;
    __builtin_memcpy(&f, &u, 4);
    return f;
}
__device__ __forceinline__ float i2f(int u) {
    float f;
    __builtin_memcpy(&f, &u, 4);
    return f;
}
__device__ __forceinline__ int f2i(float f) {
    int u;
    __builtin_memcpy(&u, &f, 4);
    return u;
}

// ---------- fp8 e4m3fn encode ----------
__device__ __forceinline__ unsigned char f8enc(float x) {
#if __has_builtin(__builtin_amdgcn_cvt_pk_fp8_f32)
    int pk = __builtin_amdgcn_cvt_pk_fp8_f32(x, 0.0f, 0, false);
    return (unsigned char)(pk & 0xff);
#else
    // manual OCP e4m3fn (RNE): max 448, min normal 2^-6, subnormal step 2^-9
    unsigned u;
    __builtin_memcpy(&u, &x, 4);
    unsigned s = (u >> 31) << 7;
    float a = fabsf(x);
    if (!(a > 0.0f)) return (unsigned char)s;
    if (a >= 464.0f) return (unsigned char)(s | 0x7E);
    if (a < 0.015625f) {
        int q = (int)rintf(a * 512.0f);
        return (unsigned char)(s | (unsigned)q);
    }
    int ex;
    (void)frexpf(a, &ex);
    int E = ex - 1;
    float t = ldexpf(a, -E);
    int m3 = (int)rintf((t - 1.0f) * 8.0f);
    if (m3 == 8) { m3 = 0; E += 1; }
    if (E > 8) return (unsigned char)(s | 0x7E);
    return (unsigned char)(s | ((unsigned)(E + 7) << 3) | (unsigned)m3);
#endif
}

// lgkm-only barrier: LDS visibility without draining vmcnt.
// imm 0xC07F = vmcnt(63) expcnt(7) lgkmcnt(0).
__device__ __forceinline__ void barrier_lds_only() {
    __builtin_amdgcn_s_waitcnt(0xC07F);
    __builtin_amdgcn_s_barrier();
}

// =====================================================================
// K0: one-time weight conversion.
// i < 131072:    whh (fp32 [512][128], both dirs) -> fp8 e4m3 scaled x64.
// i >= 131072:   w_ih (both dirs) -> bf16, PACKED-PERMUTED rows:
//                wihP[dir][np][k] = bf16(w_ih_dir[((np&3)<<7)+(np>>2)][k])
//                so k_inproj's B staging is a raw copy (no cvt, no permute).
// =====================================================================
__global__ __launch_bounds__(256) void k_wcvt(
    const float* __restrict__ wf, const float* __restrict__ wb,
    const float* __restrict__ wih_f, const float* __restrict__ wih_b,
    unsigned char* __restrict__ o, unsigned short* __restrict__ wihP)
{
    const int i = blockIdx.x * 256 + threadIdx.x;   // 0 .. 262143
    if (i < 131072) {
        const float v = (i < 65536) ? wf[i] : wb[i - 65536];
        o[i] = f8enc(v * 64.0f);
    } else {
        const int j = i - 131072;                   // 0 .. 131071
        const int dir = j >> 16;
        const int np = (j >> 7) & 511;
        const int k = j & 127;
        const int norig = ((np & 3) << 7) + (np >> 2);
        const float* w = dir ? wih_b : wih_f;
        wihP[j] = f2bf_hw(w[norig * 128 + k]);
    }
}

// =====================================================================
// K1: input projection via bf16 MFMA — R17 structure (unchanged).
// Grid 512 (one WG per 128-row tile). A staged ONCE; loop over the
// 8 (dir,nt) B-chunks with double-buffered LDS B. B pre-converted bf16
// packed-permuted by k_wcvt => staging is pure uint4 copies.
// G stored pre-scaled by log2e (i,f,o) / 2*log2e (g), layout [t][b][j][gate].
// G-store coalescing note: per row, wave w's ni-pair fills the aligned
// 64B line [w*32 .. w*32+32) ushorts => writes already line-efficient.
// =====================================================================
__global__ __launch_bounds__(256) void k_inproj(
    const int* __restrict__ sent, const float* __restrict__ embed,
    const unsigned short* __restrict__ wihP,
    const float* __restrict__ b_ih_f, const float* __restrict__ b_hh_f,
    const float* __restrict__ b_ih_b, const float* __restrict__ b_hh_b,
    unsigned short* __restrict__ G_f, unsigned short* __restrict__ G_b)
{
    __shared__ unsigned short Asm[128][136];
    __shared__ unsigned short Bsm[2][128][136];
    const int tid = threadIdx.x;
    const int mt = blockIdx.x;
    const int r0 = mt * 128;

    // ---- stage A once: rows r0..r0+127 of embed[token] as bf16 ----
    {
        const int srow = tid >> 1;
        const int ch = (tid & 1) * 64;
        const int rg = r0 + srow;
        const int tt = rg >> 6, bb = rg & 63;
        const int tok = sent[bb * Tn + tt];
        const float* ar = embed + (size_t)tok * En + ch;
#pragma unroll
        for (int i = 0; i < 64; i += 4) {
            float4 v = *(const float4*)(ar + i);
            *(unsigned*)&Asm[srow][ch + i]     = cvt_pk_bf16(v.x, v.y);
            *(unsigned*)&Asm[srow][ch + i + 2] = cvt_pk_bf16(v.z, v.w);
        }
    }

    // ---- B chunk staging: raw bf16 copy (128 rows x 128 cols) ----
    const int brow = tid >> 1;
    const int bhalf = (tid & 1) * 64;
#define STAGE_B(cidx)                                                          \
    {                                                                          \
        const int d_ = (cidx) >> 2, nt_ = (cidx) & 3, pb_ = (cidx) & 1;        \
        const uint4* s4 = (const uint4*)(wihP + ((size_t)d_ << 16) +           \
                          (size_t)(nt_ * 128 + brow) * 128 + bhalf);           \
        uint4* d4 = (uint4*)&Bsm[pb_][brow][bhalf];                            \
        _Pragma("unroll")                                                      \
        for (int ii = 0; ii < 8; ++ii) d4[ii] = s4[ii];                        \
    }

    STAGE_B(0);
    __syncthreads();

    const int w = tid >> 6, lane = tid & 63;
    const int ln = lane & 15, lq = lane >> 4;
    const int nwb = w * 32;

    for (int cidx = 0; cidx < 8; ++cidx) {
        if (cidx + 1 < 8) STAGE_B(cidx + 1);   // prefetch next chunk (other buffer)
        const int dir = cidx >> 2, nt = cidx & 3, pb = cidx & 1;

        fl4 acc[8][2];
#pragma unroll
        for (int mi = 0; mi < 8; ++mi)
#pragma unroll
            for (int ni = 0; ni < 2; ++ni) acc[mi][ni] = (fl4){0.f, 0.f, 0.f, 0.f};

#pragma unroll
        for (int kt = 0; kt < 4; ++kt) {
            const int kc = kt * 32 + lq * 8;
            bh8 a[8], bf[2];
#pragma unroll
            for (int mi = 0; mi < 8; ++mi) a[mi] = *(const bh8*)&Asm[mi * 16 + ln][kc];
#pragma unroll
            for (int ni = 0; ni < 2; ++ni) bf[ni] = *(const bh8*)&Bsm[pb][nwb + ni * 16 + ln][kc];
#pragma unroll
            for (int mi = 0; mi < 8; ++mi)
#pragma unroll
                for (int ni = 0; ni < 2; ++ni)
                    acc[mi][ni] = __builtin_amdgcn_mfma_f32_16x16x32_bf16(a[mi], bf[ni], acc[mi][ni], 0, 0, 0);
        }

        const float* bi = dir ? b_ih_b : b_ih_f;
        const float* bh = dir ? b_hh_b : b_hh_f;
        unsigned short* Gout = dir ? G_b : G_f;

        float bias[2], gsc[2];
#pragma unroll
        for (int ni = 0; ni < 2; ++ni) {
            const int np = nt * 128 + nwb + ni * 16 + ln;   // packed index j*4+gate
            const int norig = ((np & 3) << 7) + (np >> 2);
            bias[ni] = bi[norig] + bh[norig];
            gsc[ni] = ((np & 3) == 2) ? LOG2E2 : LOG2E;     // gate g gets 2*log2e
        }
#pragma unroll
        for (int mi = 0; mi < 8; ++mi)
#pragma unroll
            for (int ni = 0; ni < 2; ++ni) {
                const int np = nt * 128 + nwb + ni * 16 + ln;
#pragma unroll
                for (int rg = 0; rg < 4; ++rg) {
                    const int m = mi * 16 + lq * 4 + rg;
                    const size_t r = (size_t)(r0 + m);
                    Gout[(r << 9) + np] = f2bf_hw((acc[mi][ni][rg] + bias[ni]) * gsc[ni]);
                }
            }

        __syncthreads();   // chunk done: staged buffer ready, old buffer free
    }
#undef STAGE_B
}

// =====================================================================
// K2: LSTM recurrence — R21 structure RESTORED (349.0 us, 691.4 total).
// Structural ledger (do NOT retry): R13 lockstep dual-dir (1008us);
// R18 spin-poll dual-dir (646us + 31ms stalls); R22 setprio-over-
// ds_read+waitcnt + quad-split stores (383us + 40.9ms stall — never
// enclose a waitcnt in a priority window; setprio wraps ONLY the MFMA
// cluster with the feeding load already issued). 2-chains-per-CU pays
// ~+598cyc issue to hide <=290cyc latency => dead. Wave-split variants
// dead by redundancy arithmetic. Multi-batch-per-WG can't cut wall.
// fp4/fp6-rate paths need low-precision h => dead.
// Step model ~820 cyc: 276 MFMA-issue + ~280 VALU/TRANS-issue +
// ~260 serial-chain latency.
// =====================================================================
__global__ __launch_bounds__(512, 2) void k_lstm(
    const unsigned char* __restrict__ whh8,
    const unsigned short* __restrict__ G_f, const unsigned short* __restrict__ G_b,
    unsigned short* __restrict__ h_f, unsigned short* __restrict__ h_b)
{
    const int tid = threadIdx.x;
    const int w = tid >> 6;
    const int lane = tid & 63;
    const int ln = lane & 15;
    const int quad = lane >> 4;
    const int b = blockIdx.x;           // batch
    const int dir = blockIdx.y;
    const unsigned short* Gd = dir ? G_b : G_f;
    unsigned short* ho = dir ? h_b : h_f;

    const int j = w * 16 + ln;          // this lane's h index (gate column)

    __shared__ __align__(16) unsigned char hls8[2][128];   // fp8 h (x16), double-buffered

    // ---- weights (B-frags): lane provides B[k=quad*32+i][n=ln] = W8[q*128+j][quad*32+i]
    const unsigned char* wb8 = whh8 + (size_t)dir * 65536 + quad * 32;
    const i8v w0 = *(const i8v*)(wb8 + ((size_t)(0 * 128 + j) << 7));
    const i8v w1 = *(const i8v*)(wb8 + ((size_t)(1 * 128 + j) << 7));
    const i8v w2 = *(const i8v*)(wb8 + ((size_t)(2 * 128 + j) << 7));
    const i8v w3 = *(const i8v*)(wb8 + ((size_t)(3 * 128 + j) << 7));

    // zero both h buffers (2*128 fp8 = 64 dwords); fp8 0x00 == 0.0
    if (tid < 64) ((unsigned*)hls8)[tid] = 0u;
    float c = 0.0f;
    __syncthreads();

    // ---- running pointers (strength-reduced; dir sign hoisted) ----
    const int t0 = dir ? (Tn - 1) : 0;
    const ptrdiff_t gstep = dir ? -(ptrdiff_t)(Bn << 9) : (ptrdiff_t)(Bn << 9);   // ushorts/step
    const ptrdiff_t hstep = dir ? -(ptrdiff_t)(Bn << 7) : (ptrdiff_t)(Bn << 7);   // ushorts/step
    const unsigned short* gptr = Gd + (((size_t)t0 * Bn + b) << 9) + (j << 2);
    unsigned short* hptr = ho + (((size_t)t0 * Bn + b) << 7) + j;

    // ---- G pipeline preload: slot u = packed gates [i|f] [g|o] of step u ----
    uint2 gp[4];
#pragma unroll
    for (int u = 0; u < 4; ++u) {
        gp[u] = *(const uint2*)gptr;
        gptr += gstep;
    }
    // gptr now points at step 4

    const float dsL  = 0.0009765625f * LOG2E;    // 1/(64*16) descale, log2e-folded
    const float ds2L = 0.0009765625f * LOG2E2;   // g-gate descale

    // ---- lane-constant activation params (quad q owns gate q) ----
    const float cds = (quad == 2) ? ds2L : -dsL;
    const unsigned gsign = (quad == 2) ? 0u : 0x80000000u;
    const int gshift = (quad & 1) ? 0 : 16;
    const int bp0 = (0 * 16 + ln) << 2;     // bpermute byte addrs (lane*4)
    const int bp1 = (1 * 16 + ln) << 2;
    const int bp2 = (2 * 16 + ln) << 2;
    const int bp3 = (3 * 16 + ln) << 2;

    for (int blk = 0; blk < Tn / 4; ++blk) {
#pragma unroll
        for (int u = 0; u < 4; ++u) {
            const int s = blk * 4 + u;
            const int p = u & 1;          // h buffer parity (blk*4 is even)

            // consume slot u (loaded at step s-4)
            const uint2 gv = gp[u];

            // prefetch step s+4 into slot u (running pointer, static slot)
            if (s + 4 < Tn) {
                gp[u] = *(const uint2*)gptr;
                gptr += gstep;
            }

            // ---- A-frag: 32 fp8 of h, k = quad*32 .. +32 (broadcast across ln)
            const i8v ha = *(const i8v*)&hls8[p][quad * 32];

            // ---- 4 INDEPENDENT K=128 fp8 MFMAs: aq = dot(h, W[q*128+j]) * 1024
            const fl4 z = (fl4){0.f, 0.f, 0.f, 0.f};
            __builtin_amdgcn_s_setprio(1);
            fl4 a0 = __builtin_amdgcn_mfma_scale_f32_16x16x128_f8f6f4(
                         ha, w0, z, 0, 0, 0, 0x7F7F7F7F, 0, 0x7F7F7F7F);
            fl4 a1 = __builtin_amdgcn_mfma_scale_f32_16x16x128_f8f6f4(
                         ha, w1, z, 0, 0, 0, 0x7F7F7F7F, 0, 0x7F7F7F7F);
            fl4 a2 = __builtin_amdgcn_mfma_scale_f32_16x16x128_f8f6f4(
                         ha, w2, z, 0, 0, 0, 0x7F7F7F7F, 0, 0x7F7F7F7F);
            fl4 a3 = __builtin_amdgcn_mfma_scale_f32_16x16x128_f8f6f4(
                         ha, w3, z, 0, 0, 0, 0x7F7F7F7F, 0, 0x7F7F7F7F);
            __builtin_amdgcn_s_setprio(0);

            // ---- quad-specialized activation: own gate only ----
            float a01 = (quad & 1) ? a1[0] : a0[0];
            float a23 = (quad & 1) ? a3[0] : a2[0];
            float aown = (quad & 2) ? a23 : a01;
            unsigned wsel = (quad & 2) ? gv.y : gv.x;
            unsigned gb = ((wsel << gshift) & 0xffff0000u) ^ gsign;
            float pre = __builtin_fmaf(aown, cds, asf(gb));
            float tq = RCP(1.0f + EXP2(pre));
            // gather all four gate results to every lane (wave crossbar)
            int tqi = f2i(tq);
            float iv = i2f(__builtin_amdgcn_ds_bpermute(bp0, tqi));
            float fv = i2f(__builtin_amdgcn_ds_bpermute(bp1, tqi));
            float tg = i2f(__builtin_amdgcn_ds_bpermute(bp2, tqi));
            float ov = i2f(__builtin_amdgcn_ds_bpermute(bp3, tqi));
            float ov16 = ov * 16.0f;                       // off-chain pow2 scale
            float gvv = __builtin_fmaf(-2.0f, tg, 1.0f);
            c = __builtin_fmaf(fv, c, iv * gvv);
            float r2 = RCP(1.0f + EXP2(c * LOG2E2));
            float th = __builtin_fmaf(-2.0f, r2, 1.0f);

            // ---- h writes (quad==0 lanes cover all 128 j): LDS fp8(x16) + global bf16
            if (quad == 0) {
                hls8[1 - p][j] = f8enc(ov16 * th);         // == f8enc((ov*th)*16)
                *hptr = f2bf_hw(ov * th);
            }
            hptr += hstep;

            barrier_lds_only();
        }
    }
}

// =====================================================================
// K3: feats. Output layout featsT[b][t][n] (b*9216 + t*9 + n) so
// k_viterbi's per-batch staging is contiguous float4 loads.
// =====================================================================
__global__ __launch_bounds__(256) void k_feats(
    const unsigned short* __restrict__ h_f, const unsigned short* __restrict__ h_b,
    const float* __restrict__ w_out, const float* __restrict__ b_out,
    float* __restrict__ feats)
{
    __shared__ float wl[256][12];
    __shared__ float bl[12];
    const int tid = threadIdx.x;
#pragma unroll
    for (int s = 0; s < 9; ++s) wl[tid][s] = w_out[s * 256 + tid];
#pragma unroll
    for (int s = 9; s < 12; ++s) wl[tid][s] = 0.0f;
    if (tid < 12) bl[tid] = (tid < 9) ? b_out[tid] : 0.0f;
    __syncthreads();

    const int r = blockIdx.x * 256 + tid;
    const unsigned short* hfr = h_f + (size_t)r * 128;
    const unsigned short* hbr = h_b + (size_t)r * 128;
    float acc[12];
#pragma unroll
    for (int k = 0; k < 12; ++k) acc[k] = bl[k];

    for (int ch = 0; ch < 32; ++ch) {
        const unsigned short* src = (ch < 16) ? (hfr + ch * 8) : (hbr + (ch - 16) * 8);
        uint4 hv = *(const uint4*)src;
        unsigned int hw0 = hv.x, hw1 = hv.y, hw2 = hv.z, hw3 = hv.w;
        const int jb = ch * 8;
#pragma unroll
        for (int q = 0; q < 8; ++q) {
            unsigned int word = (q < 2) ? hw0 : ((q < 4) ? hw1 : ((q < 6) ? hw2 : hw3));
            unsigned short hs = (q & 1) ? (unsigned short)(word >> 16) : (unsigned short)(word & 0xffff);
            float hf = bf2f(hs);
            const float* wrp = &wl[jb + q][0];
            float4 w0 = *(const float4*)(wrp);
            float4 w1 = *(const float4*)(wrp + 4);
            float4 w2 = *(const float4*)(wrp + 8);
            acc[0] += hf * w0.x; acc[1] += hf * w0.y; acc[2] += hf * w0.z; acc[3] += hf * w0.w;
            acc[4] += hf * w1.x; acc[5] += hf * w1.y; acc[6] += hf * w1.z; acc[7] += hf * w1.w;
            acc[8] += hf * w2.x; acc[9] += hf * w2.y; acc[10] += hf * w2.z; acc[11] += hf * w2.w;
        }
    }
    const int t = r >> 6, b = r & 63;                 // r = t*64 + b
    float* fr = feats + (size_t)b * 9216 + (size_t)t * 9;
#pragma unroll
    for (int k = 0; k < 9; ++k) fr[k] = acc[k];
}

// =====================================================================
// K4: Viterbi (R21: running pointers, max3 chain, eq-cascade
// backpointer, coalesced featsT staging — unchanged).
// =====================================================================
__global__ __launch_bounds__(64) void k_viterbi(
    const float* __restrict__ feats, const float* __restrict__ trans,
    float* __restrict__ out)
{
    __shared__ __align__(16) unsigned char bp[1024 * 16];
    __shared__ __align__(16) float fl[1024 * 9];
    __shared__ unsigned char pt[1024];    // also absorbs the t=1023 overread of fl

    const int b = blockIdx.x, tid = threadIdx.x;

    // coalesced staging: featsT[b][0..9215] contiguous, 16B per lane
    {
        const float4* fsrc = (const float4*)(feats + (size_t)b * 9216);
        float4* fdst = (float4*)fl;
        for (int i = tid; i < 2304; i += 64) fdst[i] = fsrc[i];
    }

    const int n9 = (tid < 9) ? tid : 8;   // clamp so inactive lanes stay valid
    float trn[9];
#pragma unroll
    for (int p = 0; p < 9; ++p) trn[p] = trans[n9 * 9 + p];
    float trs = (tid < 9) ? trans[8 * 9 + tid] : -3.0e38f;

    float delta = (n9 == 7) ? 0.0f : NEGV;   // START=7
    __syncthreads();

    const float* fp = &fl[n9];                // running feats pointer
    unsigned char* bpp = &bp[tid];            // running bp pointer
    float fnext = *fp;                        // feats for t=0
    for (int t = 0; t < 1024; ++t) {
        // gather all 9 previous deltas (in-register wave crossbar)
        float d0 = __shfl(delta, 0, 64);
        float d1 = __shfl(delta, 1, 64);
        float d2 = __shfl(delta, 2, 64);
        float d3 = __shfl(delta, 3, 64);
        float d4 = __shfl(delta, 4, 64);
        float d5 = __shfl(delta, 5, 64);
        float d6 = __shfl(delta, 6, 64);
        float d7 = __shfl(delta, 7, 64);
        float d8 = __shfl(delta, 8, 64);
        float fhere = fnext;
        fp += 9;
        fnext = *fp;                          // t=1023: lands in pt[], unused

        float s0 = d0 + trn[0], s1 = d1 + trn[1], s2 = d2 + trn[2];
        float s3 = d3 + trn[3], s4 = d4 + trn[4], s5 = d5 + trn[5];
        float s6 = d6 + trn[6], s7 = d7 + trn[7], s8 = d8 + trn[8];

        // recurrence chain: max via fused max3 levels (exact)
        float m012 = fmaxf(fmaxf(s0, s1), s2);
        float m345 = fmaxf(fmaxf(s3, s4), s5);
        float m678 = fmaxf(fmaxf(s6, s7), s8);
        float m = fmaxf(fmaxf(m012, m345), m678);
        delta = m + fhere;

        // backpointer: eq-match cascade (descending) -> first index == m
        int am = 8;
        am = (s7 == m) ? 7 : am;
        am = (s6 == m) ? 6 : am;
        am = (s5 == m) ? 5 : am;
        am = (s4 == m) ? 4 : am;
        am = (s3 == m) ? 3 : am;
        am = (s2 == m) ? 2 : am;
        am = (s1 == m) ? 1 : am;
        am = (s0 == m) ? 0 : am;

        if (tid < 9) *bpp = (unsigned char)am;
        bpp += 16;
    }

    float tv = (tid < 9) ? (delta + trs) : -3.0e38f;
    int bi = tid;
#pragma unroll
    for (int off = 8; off >= 1; off >>= 1) {
        float ov = __shfl_down(tv, off, 64);
        int oi = __shfl_down(bi, off, 64);
        if (ov > tv || (ov == tv && oi < bi)) { tv = ov; bi = oi; }
    }
    int best = __shfl(bi, 0, 64);
    if (tid == 0) out[b] = tv;

    if (tid == 0) {
        int tag = best;
        for (int t0 = 1023; t0 >= 0; t0 -= 8) {
            uint4 rows[8];
#pragma unroll
            for (int i = 0; i < 8; ++i) rows[i] = *(const uint4*)&bp[(t0 - i) * 16];
#pragma unroll
            for (int i = 0; i < 8; ++i) {
                pt[t0 - i] = (unsigned char)tag;
                uint4 rw = rows[i];
                unsigned int sel = (unsigned int)tag >> 2;
                unsigned int word = (sel == 0) ? rw.x : ((sel == 1) ? rw.y : rw.z);
                tag = (int)((word >> ((tag & 3) * 8)) & 0xffu);
            }
        }
    }
    for (int i = tid; i < 1024; i += 64) {
        out[64 + b * 1024 + i] = (float)pt[i];
    }
}

// =====================================================================
extern "C" void kernel_launch(void* const* d_in, const int* in_sizes, int n_in,
                              void* d_out, int out_size, void* d_ws, size_t ws_size,
                              hipStream_t stream) {
    const int*   sent   = (const int*)d_in[0];
    const float* embed  = (const float*)d_in[1];
    const float* w_ih_f = (const float*)d_in[2];
    const float* w_hh_f = (const float*)d_in[3];
    const float* b_ih_f = (const float*)d_in[4];
    const float* b_hh_f = (const float*)d_in[5];
    const float* w_ih_b = (const float*)d_in[6];
    const float* w_hh_b = (const float*)d_in[7];
    const float* b_ih_b = (const float*)d_in[8];
    const float* b_hh_b = (const float*)d_in[9];
    const float* w_out  = (const float*)d_in[10];
    const float* b_out  = (const float*)d_in[11];
    const float* trans  = (const float*)d_in[12];
    float* out = (float*)d_out;

    unsigned short* G_f = (unsigned short*)d_ws;
    unsigned short* G_b = G_f + (size_t)Tn * Bn * G4;
    unsigned short* h_f = G_b + (size_t)Tn * Bn * G4;
    unsigned short* h_b = h_f + (size_t)Tn * Bn * 128;
    float* feats = (float*)(h_b + (size_t)Tn * Bn * 128);
    unsigned char* whh8 = (unsigned char*)(feats + (size_t)Tn * Bn * 9);
    unsigned short* wihP = (unsigned short*)(whh8 + 131072);

    k_wcvt<<<1024, 256, 0, stream>>>(w_hh_f, w_hh_b, w_ih_f, w_ih_b, whh8, wihP);
    k_inproj<<<512, 256, 0, stream>>>(sent, embed, wihP,
        b_ih_f, b_hh_f, b_ih_b, b_hh_b, G_f, G_b);
    k_lstm<<<dim3(64, 2), 512, 0, stream>>>(whh8, G_f, G_b, h_f, h_b);
    k_feats<<<256, 256, 0, stream>>>(h_f, h_b, w_out, b_out, feats);
    k_viterbi<<<64, 64, 0, stream>>>(feats, trans, out);
}